// Round 17
// baseline (89.810 us; speedup 1.0000x reference)
//
#include <hip/hip_runtime.h>
#include <hip/hip_bf16.h>
#include <math.h>

#define NEG_SLOPE 0.2f
#define EPS_F 1e-16f
#define PCAP 4096       // per-partition record capacity (mean ~2046, ~45 sigma)
#define NPMAX 512       // max partitions (N <= 65536)

typedef float f32x4 __attribute__((ext_vector_type(4)));
typedef short bf16x8 __attribute__((ext_vector_type(8)));

__device__ __forceinline__ unsigned int pk2bf(float a, float b) {
    unsigned int ua = __float_as_uint(a), ub = __float_as_uint(b);
    ua = (ua + 0x7fffu + ((ua >> 16) & 1u)) >> 16;
    ub = (ub + 0x7fffu + ((ub >> 16) & 1u)) >> 16;
    return ua | (ub << 16);
}
__device__ __forceinline__ unsigned short f2bf(float f) {
    unsigned int u = __float_as_uint(f);
    return (unsigned short)((u + 0x7fffu + ((u >> 16) & 1u)) >> 16);
}
__device__ __forceinline__ float bf_lo(unsigned int p) { return __uint_as_float(p << 16); }
__device__ __forceinline__ float bf_hi(unsigned int p) { return __uint_as_float(p & 0xffff0000u); }

// ---------------- prep: Wt[col][k] bf16 (+ Wa rows 128..135, zeros) + pcnt zero --
__global__ void k_prep(const float* __restrict__ W,
                       const float* __restrict__ att_src, const float* __restrict__ att_dst,
                       unsigned short* __restrict__ Wtb, int* __restrict__ pcnt) {
    int b = blockIdx.x, t = threadIdx.x;
    if (b < 64) {
        int id = b * 256 + t;        // 0..16383
        int k = id >> 7, col = id & 127;
        Wtb[col * 128 + k] = f2bf(W[id]);
    } else if (b == 64) {
        int k4 = t >> 3, j = t & 7;  // k4: 0..31
        const float* att = (j < 4) ? att_src : att_dst;
        int h = j & 3;
        #pragma unroll
        for (int kk = 0; kk < 4; kk++) {
            int k = k4 * 4 + kk;
            float s = 0.f;
            #pragma unroll
            for (int c = 0; c < 32; c++)
                s = fmaf(W[k * 128 + h * 32 + c], att[h * 32 + c], s);
            Wtb[(128 + j) * 128 + k] = f2bf(s);
        }
        for (int idx = t; idx < 1024; idx += 256)
            Wtb[(136 + (idx >> 7)) * 128 + (idx & 127)] = 0;
    } else {
        pcnt[t] = 0;
        pcnt[t + 256] = 0;
    }
}

// ================= fused: radix-partition (blocks [0,nPB)) + MFMA GEMM ===========
__global__ __launch_bounds__(256)
void k_pg(const unsigned int* __restrict__ eidx,
          int* __restrict__ pcnt, unsigned int* __restrict__ rec, int E, int npart,
          const float* __restrict__ x, const unsigned short* __restrict__ Wtb,
          unsigned short* __restrict__ hb,
          float* __restrict__ a_src, float* __restrict__ a_dst, int N, int nPB) {
    __shared__ __align__(16) char smem[53248];
    int t = threadIdx.x;

    if ((int)blockIdx.x < nPB) {
        // ---------------- part2: edges -> per-partition record runs ---------------
        int* hist = (int*)smem;
        int* base = (int*)(smem + 2048);
        int* sflagp = (int*)(smem + 4096);
        if (t < 64) {   // dtype detect: odd 32b words all zero => int64
            unsigned int v = eidx[2 * t + 1];
            #pragma unroll
            for (int m = 1; m <= 32; m <<= 1) v |= __shfl_xor(v, m);
            if (t == 0) *sflagp = (v == 0u) ? 1 : 0;
        }
        for (int p = t; p < npart; p += 256) hist[p] = 0;
        __syncthreads();
        int flag = *sflagp;
        const uint2* e2p = (const uint2*)eidx;
        int e0 = blockIdx.x * 4096;
        int se[16], de[16];
        #pragma unroll
        for (int i = 0; i < 16; i++) {
            int idx = e0 + t + i * 256;
            de[i] = -1;
            if (idx < E) {
                if (flag) { se[i] = (int)e2p[idx].x; de[i] = (int)e2p[E + idx].x; }
                else      { se[i] = (int)eidx[idx];  de[i] = (int)eidx[E + idx]; }
                atomicAdd(&hist[de[i] >> 7], 1);
            }
        }
        __syncthreads();
        for (int p = t; p < npart; p += 256) {
            int c = hist[p];
            base[p] = c ? atomicAdd(&pcnt[p], c) : 0;
            hist[p] = 0;
        }
        __syncthreads();
        #pragma unroll
        for (int i = 0; i < 16; i++) {
            if (de[i] >= 0) {
                int p = de[i] >> 7;
                int r = atomicAdd(&hist[p], 1);
                int pos = base[p] + r;
                if (pos < PCAP)
                    rec[(size_t)p * PCAP + pos] =
                        ((unsigned int)se[i] << 7) | (unsigned int)(de[i] & 127);
            }
        }
    } else {
        // ---------------- MFMA GEMM: h(bf16) = x @ W, fused logits ----------------
        unsigned short* xlds = (unsigned short*)smem;            // 64*128  (16 KB)
        unsigned short* wlds = (unsigned short*)(smem + 16384);  // 144*128 (36 KB)
        int l = t & 63, w = t >> 6;
        int br = ((int)blockIdx.x - nPB) * 64;

        #pragma unroll
        for (int i = 0; i < 9; i++) {
            int u = t + i * 256;
            uint4 v = *(const uint4*)(Wtb + u * 8);
            int row = u >> 4;
            int e8  = (u & 15) * 8;
            *(uint4*)&wlds[row * 128 + (e8 ^ ((row & 7) << 3))] = v;
        }
        {
            int row = t >> 2, kq = t & 3;
            int gr = br + row;
            const float* xp = x + (size_t)gr * 128 + kq * 32;
            #pragma unroll
            for (int j = 0; j < 4; j++) {
                uint4 pk = make_uint4(0u, 0u, 0u, 0u);
                if (gr < N) {
                    float4 v0 = *(const float4*)(xp + j * 8);
                    float4 v1 = *(const float4*)(xp + j * 8 + 4);
                    pk.x = pk2bf(v0.x, v0.y); pk.y = pk2bf(v0.z, v0.w);
                    pk.z = pk2bf(v1.x, v1.y); pk.w = pk2bf(v1.z, v1.w);
                }
                int e8 = kq * 32 + j * 8;
                *(uint4*)&xlds[row * 128 + (e8 ^ ((row & 7) << 3))] = pk;
            }
        }
        __syncthreads();

        bf16x8 a[4];
        int arow = w * 16 + (l & 15);
        int ae   = (l >> 4) * 8;
        #pragma unroll
        for (int kc = 0; kc < 4; kc++)
            a[kc] = *(const bf16x8*)&xlds[arow * 128 + ((kc * 32 + ae) ^ ((arow & 7) << 3))];

        int rowbase = br + w * 16 + (l >> 4) * 4;

        #pragma unroll
        for (int nb = 0; nb < 9; nb++) {
            int brow = nb * 16 + (l & 15);
            f32x4 c = {0.f, 0.f, 0.f, 0.f};
            #pragma unroll
            for (int kc = 0; kc < 4; kc++) {
                bf16x8 bfr = *(const bf16x8*)&wlds[brow * 128 + ((kc * 32 + ae) ^ ((brow & 7) << 3))];
                c = __builtin_amdgcn_mfma_f32_16x16x32_bf16(a[kc], bfr, c, 0, 0, 0);
            }
            if (nb < 8) {
                #pragma unroll
                for (int r = 0; r < 4; r++) {
                    float v  = c[r];
                    float vo = __shfl_xor(v, 1);
                    int row = rowbase + r;
                    if (row < N && (l & 1) == 0)
                        *(unsigned int*)&hb[(size_t)row * 128 + nb * 16 + (l & 15)] = pk2bf(v, vo);
                }
            } else {
                int j = l & 15;
                #pragma unroll
                for (int r = 0; r < 4; r++) {
                    int row = rowbase + r;
                    if (row < N && j < 8) {
                        if (j < 4) a_src[row * 4 + j]     = c[r];
                        else       a_dst[row * 4 + j - 4] = c[r];
                    }
                }
            }
        }
    }
}

// ========== fused aggregate: per-partition LDS counting sort + gather ===========
#define BATCH4(bk, j, ad, den, ax, ay)                                          \
    {                                                                            \
        int s0=(int)bk[j], s1=(int)bk[j+1], s2=(int)bk[j+2], s3=(int)bk[j+3];    \
        float a0=a_src[s0*4+head], a1=a_src[s1*4+head];                          \
        float a2=a_src[s2*4+head], a3=a_src[s3*4+head];                          \
        unsigned int p0=*(const unsigned int*)&hb[(size_t)s0*128+c0];            \
        unsigned int p1=*(const unsigned int*)&hb[(size_t)s1*128+c0];            \
        unsigned int p2=*(const unsigned int*)&hb[(size_t)s2*128+c0];            \
        unsigned int p3=*(const unsigned int*)&hb[(size_t)s3*128+c0];            \
        float e0=a0+ad; e0=fmaxf(e0,NEG_SLOPE*e0); float w0=__expf(e0);          \
        float e1=a1+ad; e1=fmaxf(e1,NEG_SLOPE*e1); float w1=__expf(e1);          \
        float e2=a2+ad; e2=fmaxf(e2,NEG_SLOPE*e2); float w2=__expf(e2);          \
        float e3=a3+ad; e3=fmaxf(e3,NEG_SLOPE*e3); float w3=__expf(e3);          \
        den += (w0+w1)+(w2+w3);                                                  \
        ax = fmaf(w0,bf_lo(p0),ax); ay = fmaf(w0,bf_hi(p0),ay);                  \
        ax = fmaf(w1,bf_lo(p1),ax); ay = fmaf(w1,bf_hi(p1),ay);                  \
        ax = fmaf(w2,bf_lo(p2),ax); ay = fmaf(w2,bf_hi(p2),ay);                  \
        ax = fmaf(w3,bf_lo(p3),ax); ay = fmaf(w3,bf_hi(p3),ay);                  \
    }

#define ONEEDGE(bk, j, ad, den, ax, ay)                                          \
    {                                                                            \
        int s0=(int)bk[j];                                                       \
        float a0=a_src[s0*4+head];                                               \
        unsigned int p0=*(const unsigned int*)&hb[(size_t)s0*128+c0];            \
        float e0=a0+ad; e0=fmaxf(e0,NEG_SLOPE*e0); float w0=__expf(e0);          \
        den += w0;                                                               \
        ax = fmaf(w0,bf_lo(p0),ax); ay = fmaf(w0,bf_hi(p0),ay);                  \
    }

__global__ __launch_bounds__(512)
void k_agg(const int* __restrict__ pcnt, const unsigned int* __restrict__ rec,
           const float* __restrict__ a_src, const float* __restrict__ a_dst,
           const unsigned short* __restrict__ hb, const float* __restrict__ bias,
           float* __restrict__ out, int N) {
    __shared__ int hist[128];     // deg per node
    __shared__ int start[128];    // exclusive offsets
    __shared__ int cur[128];
    __shared__ unsigned int ssort[PCAP];   // 16 KB, node-grouped src lists
    int p = blockIdx.x, t = threadIdx.x;

    // ---- phase 1: counting sort of this partition's records into LDS ----
    if (t < 128) { hist[t] = 0; cur[t] = 0; }
    __syncthreads();
    int cnt = min(pcnt[p], PCAP);
    const unsigned int* rb = rec + (size_t)p * PCAP;
    for (int i = t; i < cnt; i += 512) atomicAdd(&hist[rb[i] & 127], 1);
    __syncthreads();
    if (t < 128) start[t] = hist[t];
    __syncthreads();
    #pragma unroll
    for (int off = 1; off < 128; off <<= 1) {
        int u = (t < 128 && t >= off) ? start[t - off] : 0;
        __syncthreads();
        if (t < 128) start[t] += u;
        __syncthreads();
    }
    if (t < 128) start[t] -= hist[t];   // exclusive
    __syncthreads();
    for (int i = t; i < cnt; i += 512) {
        unsigned int r = rb[i];
        int n = r & 127;
        int pos = start[n] + atomicAdd(&cur[n], 1);
        ssort[pos] = r >> 7;
    }
    __syncthreads();

    // ---- phase 2: gather-aggregate, 2 nodes per wave-iteration ----
    int wave = t >> 6;
    int lane = t & 63;
    int c0 = lane * 2;
    int head = lane >> 4;
    float2 b2 = *(const float2*)&bias[c0];

    #pragma unroll 1
    for (int pair = 0; pair < 8; pair++) {
        int nA = wave * 16 + pair * 2;
        int nB = nA + 1;
        int dA = (p << 7) + nA;
        int dB = dA + 1;
        if (dA >= N) continue;
        bool vB = dB < N;

        float adA, denA, axA, ayA; const unsigned int* bkA; int gA;
        {
            adA = a_dst[dA * 4 + head];
            float es = a_src[dA * 4 + head] + adA;
            es = fmaxf(es, NEG_SLOPE * es);
            float w = __expf(es);
            unsigned int hp = *(const unsigned int*)&hb[(size_t)dA * 128 + c0];
            denA = w; axA = w * bf_lo(hp); ayA = w * bf_hi(hp);
            bkA = ssort + start[nA]; gA = hist[nA];
        }
        float adB = 0.f, denB = 0.f, axB = 0.f, ayB = 0.f;
        const unsigned int* bkB = ssort; int gB = 0;
        if (vB) {
            adB = a_dst[dB * 4 + head];
            float es = a_src[dB * 4 + head] + adB;
            es = fmaxf(es, NEG_SLOPE * es);
            float w = __expf(es);
            unsigned int hp = *(const unsigned int*)&hb[(size_t)dB * 128 + c0];
            denB = w; axB = w * bf_lo(hp); ayB = w * bf_hi(hp);
            bkB = ssort + start[nB]; gB = hist[nB];
        }

        int jA = 0, jB = 0;
        while (jA + 4 <= gA && jB + 4 <= gB) {
            BATCH4(bkA, jA, adA, denA, axA, ayA);
            BATCH4(bkB, jB, adB, denB, axB, ayB);
            jA += 4; jB += 4;
        }
        while (jA + 4 <= gA) { BATCH4(bkA, jA, adA, denA, axA, ayA); jA += 4; }
        while (jB + 4 <= gB) { BATCH4(bkB, jB, adB, denB, axB, ayB); jB += 4; }
        while (jA < gA && jB < gB) {
            ONEEDGE(bkA, jA, adA, denA, axA, ayA);
            ONEEDGE(bkB, jB, adB, denB, axB, ayB);
            jA++; jB++;
        }
        for (; jA < gA; jA++) ONEEDGE(bkA, jA, adA, denA, axA, ayA);
        for (; jB < gB; jB++) ONEEDGE(bkB, jB, adB, denB, axB, ayB);

        {
            float rden = 1.f / (denA + EPS_F);
            float ox = fmaxf(axA * rden + b2.x, 0.f);
            float oy = fmaxf(ayA * rden + b2.y, 0.f);
            *(float2*)&out[(size_t)dA * 128 + c0] = make_float2(ox, oy);
        }
        if (vB) {
            float rden = 1.f / (denB + EPS_F);
            float ox = fmaxf(axB * rden + b2.x, 0.f);
            float oy = fmaxf(ayB * rden + b2.y, 0.f);
            *(float2*)&out[(size_t)dB * 128 + c0] = make_float2(ox, oy);
        }
    }
}

extern "C" void kernel_launch(void* const* d_in, const int* in_sizes, int n_in,
                              void* d_out, int out_size, void* d_ws, size_t ws_size,
                              hipStream_t stream) {
    const float* x        = (const float*)d_in[0];
    const unsigned int* e = (const unsigned int*)d_in[1];
    const float* W        = (const float*)d_in[2];
    const float* att_src  = (const float*)d_in[3];
    const float* att_dst  = (const float*)d_in[4];
    const float* bias     = (const float*)d_in[5];
    float* out            = (float*)d_out;

    int N = in_sizes[0] / 128;
    int E = in_sizes[1] / 2;
    int npart = (N + 127) >> 7;

    char* ws = (char*)d_ws;
    size_t off = 0;
    unsigned short* Wtb    = (unsigned short*)(ws + off); off += 144 * 128 * 2;
    unsigned short* hb     = (unsigned short*)(ws + off); off += (size_t)N * 128 * 2;
    float*          a_src  = (float*)(ws + off);          off += (size_t)N * 16;
    float*          a_dst  = (float*)(ws + off);          off += (size_t)N * 16;
    int*            pcnt   = (int*)(ws + off);            off += (size_t)NPMAX * 4;
    unsigned int*   rec    = (unsigned int*)(ws + off);   off += (size_t)npart * PCAP * 4;

    int nPB = (E + 4095) / 4096;           // part2 blocks
    int gb  = (N + 63) / 64;               // gemm blocks

    k_prep<<<66, 256, 0, stream>>>(W, att_src, att_dst, Wtb, pcnt);
    k_pg<<<nPB + gb, 256, 0, stream>>>(e, pcnt, rec, E, npart,
                                       x, Wtb, hb, a_src, a_dst, N, nPB);
    k_agg<<<npart, 512, 0, stream>>>(pcnt, rec, a_src, a_dst, hb, bias, out, N);
}

// Round 18
// 80.892 us; speedup vs baseline: 1.1102x; 1.1102x over previous
//
#include <hip/hip_runtime.h>
#include <hip/hip_bf16.h>
#include <math.h>

#define NEG_SLOPE 0.2f
#define EPS_F 1e-16f
#define PCAP 4096       // per-partition record capacity (mean ~2046, ~45 sigma)
#define NPMAX 512       // max partitions (N <= 65536)

typedef float f32x4 __attribute__((ext_vector_type(4)));
typedef short bf16x8 __attribute__((ext_vector_type(8)));

__device__ __forceinline__ unsigned int pk2bf(float a, float b) {
    unsigned int ua = __float_as_uint(a), ub = __float_as_uint(b);
    ua = (ua + 0x7fffu + ((ua >> 16) & 1u)) >> 16;
    ub = (ub + 0x7fffu + ((ub >> 16) & 1u)) >> 16;
    return ua | (ub << 16);
}
__device__ __forceinline__ unsigned short f2bf(float f) {
    unsigned int u = __float_as_uint(f);
    return (unsigned short)((u + 0x7fffu + ((u >> 16) & 1u)) >> 16);
}
__device__ __forceinline__ float bf_lo(unsigned int p) { return __uint_as_float(p << 16); }
__device__ __forceinline__ float bf_hi(unsigned int p) { return __uint_as_float(p & 0xffff0000u); }

// ================= fused front: radix-partition (blocks [0,nPB)) + prep ==========
// part2: single eidx pass, (s,d) held in registers between phases.
// record = (s << 7) | (d & 127)
__global__ __launch_bounds__(256)
void k_front(const unsigned int* __restrict__ eidx,
             int* __restrict__ pcnt, unsigned int* __restrict__ rec, int E, int npart,
             const float* __restrict__ W,
             const float* __restrict__ att_src, const float* __restrict__ att_dst,
             unsigned short* __restrict__ Wtb, int nPB) {
    __shared__ int hist[NPMAX];
    __shared__ int base[NPMAX];
    __shared__ int sflag;
    int t = threadIdx.x;

    if ((int)blockIdx.x < nPB) {
        if (t < 64) {   // dtype detect: odd 32b words all zero => int64
            unsigned int v = eidx[2 * t + 1];
            #pragma unroll
            for (int m = 1; m <= 32; m <<= 1) v |= __shfl_xor(v, m);
            if (t == 0) sflag = (v == 0u) ? 1 : 0;
        }
        for (int p = t; p < npart; p += 256) hist[p] = 0;
        __syncthreads();
        int flag = sflag;
        const uint2* e2p = (const uint2*)eidx;
        int e0 = blockIdx.x * 4096;
        int se[16], de[16];
        #pragma unroll
        for (int i = 0; i < 16; i++) {
            int idx = e0 + t + i * 256;
            de[i] = -1;
            if (idx < E) {
                if (flag) { se[i] = (int)e2p[idx].x; de[i] = (int)e2p[E + idx].x; }
                else      { se[i] = (int)eidx[idx];  de[i] = (int)eidx[E + idx]; }
                atomicAdd(&hist[de[i] >> 7], 1);
            }
        }
        __syncthreads();
        // reserve contiguous global ranges (one atomic per non-empty partition)
        for (int p = t; p < npart; p += 256) {
            int c = hist[p];
            base[p] = c ? atomicAdd(&pcnt[p], c) : 0;
            hist[p] = 0;
        }
        __syncthreads();
        #pragma unroll
        for (int i = 0; i < 16; i++) {
            if (de[i] >= 0) {
                int p = de[i] >> 7;
                int r = atomicAdd(&hist[p], 1);
                int pos = base[p] + r;
                if (pos < PCAP)
                    rec[(size_t)p * PCAP + pos] =
                        ((unsigned int)se[i] << 7) | (unsigned int)(de[i] & 127);
            }
        }
    } else {
        // ---- prep: Wt[col][k] bf16 (+ Wa rows 128..135, zeros 136..143) ----
        int b = (int)blockIdx.x - nPB;
        if (b < 64) {
            int id = b * 256 + t;        // 0..16383
            int k = id >> 7, col = id & 127;
            Wtb[col * 128 + k] = f2bf(W[id]);
        } else {
            int k4 = t >> 3, j = t & 7;  // k4: 0..31
            const float* att = (j < 4) ? att_src : att_dst;
            int h = j & 3;
            #pragma unroll
            for (int kk = 0; kk < 4; kk++) {
                int k = k4 * 4 + kk;
                float s = 0.f;
                #pragma unroll
                for (int c = 0; c < 32; c++)
                    s = fmaf(W[k * 128 + h * 32 + c], att[h * 32 + c], s);
                Wtb[(128 + j) * 128 + k] = f2bf(s);
            }
            for (int idx = t; idx < 1024; idx += 256)
                Wtb[(136 + (idx >> 7)) * 128 + (idx & 127)] = 0;
        }
    }
}

// ================= fused mid: MFMA GEMM (blocks [0,gb)) + bin2 ===================
__global__ __launch_bounds__(256)
void k_mid(const float* __restrict__ x, const unsigned short* __restrict__ Wtb,
           unsigned short* __restrict__ hb,
           float* __restrict__ a_src, float* __restrict__ a_dst, int N,
           const int* __restrict__ pcnt, const unsigned int* __restrict__ rec,
           unsigned int* __restrict__ srt, int* __restrict__ rowArr,
           int* __restrict__ degArr, int gb) {
    __shared__ __align__(16) char smem[53248];   // max(gemm 52KB, bin2 ~17.5KB)
    int t = threadIdx.x;

    if ((int)blockIdx.x < gb) {
        // ---------------- MFMA GEMM: h(bf16) = x @ W, fused logits ----------------
        unsigned short* xlds = (unsigned short*)smem;            // 64*128  (16 KB)
        unsigned short* wlds = (unsigned short*)(smem + 16384);  // 144*128 (36 KB)
        int l = t & 63, w = t >> 6;
        int br = blockIdx.x * 64;

        #pragma unroll
        for (int i = 0; i < 9; i++) {
            int u = t + i * 256;
            uint4 v = *(const uint4*)(Wtb + u * 8);
            int row = u >> 4;
            int e8  = (u & 15) * 8;
            *(uint4*)&wlds[row * 128 + (e8 ^ ((row & 7) << 3))] = v;
        }
        {
            int row = t >> 2, kq = t & 3;
            int gr = br + row;
            const float* xp = x + (size_t)gr * 128 + kq * 32;
            #pragma unroll
            for (int j = 0; j < 4; j++) {
                uint4 pk = make_uint4(0u, 0u, 0u, 0u);
                if (gr < N) {
                    float4 v0 = *(const float4*)(xp + j * 8);
                    float4 v1 = *(const float4*)(xp + j * 8 + 4);
                    pk.x = pk2bf(v0.x, v0.y); pk.y = pk2bf(v0.z, v0.w);
                    pk.z = pk2bf(v1.x, v1.y); pk.w = pk2bf(v1.z, v1.w);
                }
                int e8 = kq * 32 + j * 8;
                *(uint4*)&xlds[row * 128 + (e8 ^ ((row & 7) << 3))] = pk;
            }
        }
        __syncthreads();

        bf16x8 a[4];
        int arow = w * 16 + (l & 15);
        int ae   = (l >> 4) * 8;
        #pragma unroll
        for (int kc = 0; kc < 4; kc++)
            a[kc] = *(const bf16x8*)&xlds[arow * 128 + ((kc * 32 + ae) ^ ((arow & 7) << 3))];

        int rowbase = br + w * 16 + (l >> 4) * 4;

        #pragma unroll
        for (int nb = 0; nb < 9; nb++) {
            int brow = nb * 16 + (l & 15);
            f32x4 c = {0.f, 0.f, 0.f, 0.f};
            #pragma unroll
            for (int kc = 0; kc < 4; kc++) {
                bf16x8 bfr = *(const bf16x8*)&wlds[brow * 128 + ((kc * 32 + ae) ^ ((brow & 7) << 3))];
                c = __builtin_amdgcn_mfma_f32_16x16x32_bf16(a[kc], bfr, c, 0, 0, 0);
            }
            if (nb < 8) {
                #pragma unroll
                for (int r = 0; r < 4; r++) {
                    float v  = c[r];
                    float vo = __shfl_xor(v, 1);
                    int row = rowbase + r;
                    if (row < N && (l & 1) == 0)
                        *(unsigned int*)&hb[(size_t)row * 128 + nb * 16 + (l & 15)] = pk2bf(v, vo);
                }
            } else {
                int j = l & 15;
                #pragma unroll
                for (int r = 0; r < 4; r++) {
                    int row = rowbase + r;
                    if (row < N && j < 8) {
                        if (j < 4) a_src[row * 4 + j]     = c[r];
                        else       a_dst[row * 4 + j - 4] = c[r];
                    }
                }
            }
        }
    } else {
        // ---------------- bin2: per-partition LDS counting sort -------------------
        int* hist = (int*)smem;
        int* offs = hist + 128;
        int* cur  = offs + 128;
        unsigned int* ssort = (unsigned int*)(smem + 1536);   // 16 KB
        int p = (int)blockIdx.x - gb;
        if (t < 128) { hist[t] = 0; cur[t] = 0; }
        __syncthreads();
        int cnt = min(pcnt[p], PCAP);
        const unsigned int* rb = rec + (size_t)p * PCAP;
        for (int i = t; i < cnt; i += 256) atomicAdd(&hist[rb[i] & 127], 1);
        __syncthreads();
        if (t < 128) offs[t] = hist[t];
        __syncthreads();
        #pragma unroll
        for (int off = 1; off < 128; off <<= 1) {
            int u = (t < 128 && t >= off) ? offs[t - off] : 0;
            __syncthreads();
            if (t < 128) offs[t] += u;
            __syncthreads();
        }
        for (int i = t; i < cnt; i += 256) {
            unsigned int r = rb[i];
            int n = r & 127;
            int pos = (offs[n] - hist[n]) + atomicAdd(&cur[n], 1);
            ssort[pos] = r >> 7;
        }
        __syncthreads();
        for (int i = t; i < cnt; i += 256) srt[(size_t)p * PCAP + i] = ssort[i];
        int node = (p << 7) + t;
        if (t < 128 && node < N) {
            rowArr[node] = p * PCAP + (offs[t] - hist[t]);
            degArr[node] = hist[t];
        }
    }
}

// ---------------- gather aggregation: TWO nodes per wave -------------------------
#define BATCH4(bk, j, ad, den, ax, ay)                                          \
    {                                                                            \
        int s0=(int)bk[j], s1=(int)bk[j+1], s2=(int)bk[j+2], s3=(int)bk[j+3];    \
        float a0=a_src[s0*4+head], a1=a_src[s1*4+head];                          \
        float a2=a_src[s2*4+head], a3=a_src[s3*4+head];                          \
        unsigned int p0=*(const unsigned int*)&hb[(size_t)s0*128+c0];            \
        unsigned int p1=*(const unsigned int*)&hb[(size_t)s1*128+c0];            \
        unsigned int p2=*(const unsigned int*)&hb[(size_t)s2*128+c0];            \
        unsigned int p3=*(const unsigned int*)&hb[(size_t)s3*128+c0];            \
        float e0=a0+ad; e0=fmaxf(e0,NEG_SLOPE*e0); float w0=__expf(e0);          \
        float e1=a1+ad; e1=fmaxf(e1,NEG_SLOPE*e1); float w1=__expf(e1);          \
        float e2=a2+ad; e2=fmaxf(e2,NEG_SLOPE*e2); float w2=__expf(e2);          \
        float e3=a3+ad; e3=fmaxf(e3,NEG_SLOPE*e3); float w3=__expf(e3);          \
        den += (w0+w1)+(w2+w3);                                                  \
        ax = fmaf(w0,bf_lo(p0),ax); ay = fmaf(w0,bf_hi(p0),ay);                  \
        ax = fmaf(w1,bf_lo(p1),ax); ay = fmaf(w1,bf_hi(p1),ay);                  \
        ax = fmaf(w2,bf_lo(p2),ax); ay = fmaf(w2,bf_hi(p2),ay);                  \
        ax = fmaf(w3,bf_lo(p3),ax); ay = fmaf(w3,bf_hi(p3),ay);                  \
    }

#define ONEEDGE(bk, j, ad, den, ax, ay)                                          \
    {                                                                            \
        int s0=(int)bk[j];                                                       \
        float a0=a_src[s0*4+head];                                               \
        unsigned int p0=*(const unsigned int*)&hb[(size_t)s0*128+c0];            \
        float e0=a0+ad; e0=fmaxf(e0,NEG_SLOPE*e0); float w0=__expf(e0);          \
        den += w0;                                                               \
        ax = fmaf(w0,bf_lo(p0),ax); ay = fmaf(w0,bf_hi(p0),ay);                  \
    }

__global__ __launch_bounds__(256)
void k_aggregate(const unsigned int* __restrict__ srt, const int* __restrict__ rowArr,
                 const int* __restrict__ degArr,
                 const float* __restrict__ a_src, const float* __restrict__ a_dst,
                 const unsigned short* __restrict__ hb,
                 const float* __restrict__ bias,
                 float* __restrict__ out, int N) {
    int wave = threadIdx.x >> 6;
    int lane = threadIdx.x & 63;
    int c0 = lane * 2;
    int head = lane >> 4;
    int dA = blockIdx.x * 8 + wave * 2;
    int dB = dA + 1;
    if (dA >= N) return;
    bool vB = dB < N;

    float adA, denA, axA, ayA; const unsigned int* bkA; int gA;
    {
        adA = a_dst[dA * 4 + head];
        float es = a_src[dA * 4 + head] + adA;
        es = fmaxf(es, NEG_SLOPE * es);
        float w = __expf(es);
        unsigned int hp = *(const unsigned int*)&hb[(size_t)dA * 128 + c0];
        denA = w; axA = w * bf_lo(hp); ayA = w * bf_hi(hp);
        bkA = srt + rowArr[dA]; gA = degArr[dA];
    }
    float adB = 0.f, denB = 0.f, axB = 0.f, ayB = 0.f;
    const unsigned int* bkB = srt; int gB = 0;
    if (vB) {
        adB = a_dst[dB * 4 + head];
        float es = a_src[dB * 4 + head] + adB;
        es = fmaxf(es, NEG_SLOPE * es);
        float w = __expf(es);
        unsigned int hp = *(const unsigned int*)&hb[(size_t)dB * 128 + c0];
        denB = w; axB = w * bf_lo(hp); ayB = w * bf_hi(hp);
        bkB = srt + rowArr[dB]; gB = degArr[dB];
    }

    int jA = 0, jB = 0;
    // merged phase: 8 independent gathers in flight (4 per node)
    while (jA + 4 <= gA && jB + 4 <= gB) {
        BATCH4(bkA, jA, adA, denA, axA, ayA);
        BATCH4(bkB, jB, adB, denB, axB, ayB);
        jA += 4; jB += 4;
    }
    // solo drains
    while (jA + 4 <= gA) { BATCH4(bkA, jA, adA, denA, axA, ayA); jA += 4; }
    while (jB + 4 <= gB) { BATCH4(bkB, jB, adB, denB, axB, ayB); jB += 4; }
    // tails (interleaved when both present)
    while (jA < gA && jB < gB) {
        ONEEDGE(bkA, jA, adA, denA, axA, ayA);
        ONEEDGE(bkB, jB, adB, denB, axB, ayB);
        jA++; jB++;
    }
    for (; jA < gA; jA++) ONEEDGE(bkA, jA, adA, denA, axA, ayA);
    for (; jB < gB; jB++) ONEEDGE(bkB, jB, adB, denB, axB, ayB);

    float2 b2 = *(const float2*)&bias[c0];
    {
        float rden = 1.f / (denA + EPS_F);
        float ox = fmaxf(axA * rden + b2.x, 0.f);
        float oy = fmaxf(ayA * rden + b2.y, 0.f);
        *(float2*)&out[(size_t)dA * 128 + c0] = make_float2(ox, oy);
    }
    if (vB) {
        float rden = 1.f / (denB + EPS_F);
        float ox = fmaxf(axB * rden + b2.x, 0.f);
        float oy = fmaxf(ayB * rden + b2.y, 0.f);
        *(float2*)&out[(size_t)dB * 128 + c0] = make_float2(ox, oy);
    }
}

extern "C" void kernel_launch(void* const* d_in, const int* in_sizes, int n_in,
                              void* d_out, int out_size, void* d_ws, size_t ws_size,
                              hipStream_t stream) {
    const float* x        = (const float*)d_in[0];
    const unsigned int* e = (const unsigned int*)d_in[1];
    const float* W        = (const float*)d_in[2];
    const float* att_src  = (const float*)d_in[3];
    const float* att_dst  = (const float*)d_in[4];
    const float* bias     = (const float*)d_in[5];
    float* out            = (float*)d_out;

    int N = in_sizes[0] / 128;
    int E = in_sizes[1] / 2;
    int npart = (N + 127) >> 7;

    char* ws = (char*)d_ws;
    size_t off = 0;
    unsigned short* Wtb    = (unsigned short*)(ws + off); off += 144 * 128 * 2;
    unsigned short* hb     = (unsigned short*)(ws + off); off += (size_t)N * 128 * 2;
    float*          a_src  = (float*)(ws + off);          off += (size_t)N * 16;
    float*          a_dst  = (float*)(ws + off);          off += (size_t)N * 16;
    int*            rowArr = (int*)(ws + off);            off += (size_t)N * 4;
    int*            degArr = (int*)(ws + off);            off += (size_t)N * 4;
    int*            pcnt   = (int*)(ws + off);            off += (size_t)NPMAX * 4;
    unsigned int*   rec    = (unsigned int*)(ws + off);   off += (size_t)npart * PCAP * 4;
    unsigned int*   srt    = (unsigned int*)(ws + off);   off += (size_t)npart * PCAP * 4;

    int nPB = (E + 4095) / 4096;           // part2 blocks
    int gb  = (N + 63) / 64;               // gemm blocks

    hipMemsetAsync(pcnt, 0, (size_t)NPMAX * 4, stream);

    k_front<<<nPB + 65, 256, 0, stream>>>(e, pcnt, rec, E, npart,
                                          W, att_src, att_dst, Wtb, nPB);
    k_mid<<<gb + npart, 256, 0, stream>>>(x, Wtb, hb, a_src, a_dst, N,
                                          pcnt, rec, srt, rowArr, degArr, gb);
    k_aggregate<<<(N + 7) / 8, 256, 0, stream>>>(srt, rowArr, degArr,
                                                 a_src, a_dst, hb, bias, out, N);
}